// Round 12
// baseline (93.870 us; speedup 1.0000x reference)
//
#include <hip/hip_runtime.h>
#include <math.h>

#define NQ 12
#define DIM 4096
#define NLAYER 4
#define NT 256

typedef float v2 __attribute__((ext_vector_type(2)));
typedef unsigned int u2 __attribute__((ext_vector_type(2)));

__device__ __forceinline__ v2 mkv2(float a, float b) { v2 r; r.x = a; r.y = b; return r; }
__device__ __forceinline__ v2 sp(float a) { v2 r; r.x = a; r.y = a; return r; }
__device__ __forceinline__ v2 pkfma(v2 a, float b, v2 c) {
  return __builtin_elementwise_fma(a, sp(b), c);
}

// CNOT-cascade gather map (verified R1-R8): post-perm label y sits at sfun(y).
constexpr int sfun_c(int z) { z ^= z >> 1; z ^= z >> 2; z ^= z >> 4; z ^= z >> 8; return z & (DIM - 1); }
// Swizzle sigma (R9/R10 derivation): p0=z0^z6 p1=z1^z7 p2=z2^z8 p3=z3^z9
// p4=z4^z6^z7 p5=z5^z7. Unit-triangular -> bijective; all five access
// patterns (P, Q, Encode, Gather, Out) verified rank-6 lane-bijective.
constexpr int swz_mc(int z) {
  const int h = (z >> 6) & 63;
  return z ^ (h & 15) ^ ((h & 1) << 4) ^ ((h & 2) << 3) ^ ((h & 2) << 4);
}
__device__ __forceinline__ int sfun_d(int z) { z ^= z >> 1; z ^= z >> 2; z ^= z >> 4; z ^= z >> 8; return z & (DIM - 1); }
__device__ __forceinline__ int swz_d(int z) {
  const int h = (z >> 6) & 63;
  return z ^ (h & 15) ^ ((h & 1) << 4) ^ ((h & 2) << 3) ^ ((h & 2) << 4);
}

// Compile-time XOR byte-offset tables (sigma and sfun are GF(2)-linear).
struct KT { int P[16], Q[16], G[16]; };
constexpr KT mkKT() {
  KT k{};
  for (int j = 0; j < 16; ++j) {
    k.P[j] = swz_mc(j << 8) << 4;            // pass P: j = z{8-11}
    k.Q[j] = swz_mc(j) << 4;                 // pass Q: j = z{0-3} (also encode)
    k.G[j] = swz_mc(sfun_c(j << 8)) << 4;    // CNOT gather composed with P
  }
  return k;
}
constexpr KT KTab = mkKT();

__device__ __forceinline__ v2 block_reduce_sum2(v2 v, v2* red) {
  const int tid = threadIdx.x;
#pragma unroll
  for (int off = 32; off > 0; off >>= 1) {
    v.x += __shfl_down(v.x, off, 64);
    v.y += __shfl_down(v.y, off, 64);
  }
  if ((tid & 63) == 0) red[tid >> 6] = v;
  __syncthreads();
  if (tid == 0) {
    v2 s = sp(0.f);
#pragma unroll
    for (int i = 0; i < NT / 64; ++i) s += red[i];
    red[0] = s;
  }
  __syncthreads();
  v2 r = red[0];
  __syncthreads();
  return r;
}

// Packed complex pair update, two rows at once (v_pk_fma_f32 material).
__device__ __forceinline__ void apply_pair(v2& r0, v2& i0, v2& r1, v2& i1,
    const float2 u00, const float2 u01, const float2 u10, const float2 u11) {
  v2 nr0 = pkfma(i1, -u01.y, pkfma(r1, u01.x, pkfma(i0, -u00.y, r0 * sp(u00.x))));
  v2 ni0 = pkfma(r1,  u01.y, pkfma(i1, u01.x, pkfma(r0,  u00.y, i0 * sp(u00.x))));
  v2 nr1 = pkfma(i1, -u11.y, pkfma(r1, u11.x, pkfma(i0, -u10.y, r0 * sp(u10.x))));
  v2 ni1 = pkfma(r1,  u11.y, pkfma(i1, u11.x, pkfma(r0,  u10.y, i0 * sp(u10.x))));
  r0 = nr0; i0 = ni0; r1 = nr1; i1 = ni1;
}

// 4 register gates; slot-bit i -> qubit QTOP-i.
template <int QTOP>
__device__ __forceinline__ void gates4(v2 re[16], v2 im[16], const float2* GL) {
#pragma unroll
  for (int i = 0; i < 4; ++i) {
    const int q = QTOP - i;
    const float2 u00 = GL[q * 4 + 0], u01 = GL[q * 4 + 1];
    const float2 u10 = GL[q * 4 + 2], u11 = GL[q * 4 + 3];
#pragma unroll
    for (int pe = 0; pe < 8; ++pe) {
      const int e0 = ((pe >> i) << (i + 1)) | (pe & ((1 << i) - 1));
      const int e1 = e0 | (1 << i);
      apply_pair(re[e0], im[e0], re[e1], im[e1], u00, u01, u10, u11);
    }
  }
}

// One permlane swap with DISTINCT operands (a = reg-bit0=0 elem, b = bit0=1).
// AS/RS: probed arg-order / result-order correction (4 conventions).
template <int W, int AS, int RS>
__device__ __forceinline__ void swap_one(float& a, float& b) {
  const unsigned ua = __builtin_bit_cast(unsigned, a);
  const unsigned ub = __builtin_bit_cast(unsigned, b);
  u2 r;
  if constexpr (W == 16)
    r = __builtin_amdgcn_permlane16_swap(AS ? ub : ua, AS ? ua : ub, false, false);
  else
    r = __builtin_amdgcn_permlane32_swap(AS ? ub : ua, AS ? ua : ub, false, false);
  a = __builtin_bit_cast(float, RS ? r[1] : r[0]);
  b = __builtin_bit_cast(float, RS ? r[0] : r[1]);
}

// Exchange reg-bit0 dimension with lane-bit (W=16: bit4, W=32: bit5).
// (ext_vector elements can't bind to float& -> copy through locals.)
template <int W, int AS, int RS>
__device__ __forceinline__ void transpose_bit0(v2 re[16], v2 im[16]) {
#pragma unroll
  for (int k = 0; k < 8; ++k) {
    float arx = re[2 * k].x, brx = re[2 * k + 1].x;
    float ary = re[2 * k].y, bry = re[2 * k + 1].y;
    float aix = im[2 * k].x, bix = im[2 * k + 1].x;
    float aiy = im[2 * k].y, biy = im[2 * k + 1].y;
    swap_one<W, AS, RS>(arx, brx);
    swap_one<W, AS, RS>(ary, bry);
    swap_one<W, AS, RS>(aix, bix);
    swap_one<W, AS, RS>(aiy, biy);
    re[2 * k] = mkv2(arx, ary); re[2 * k + 1] = mkv2(brx, bry);
    im[2 * k] = mkv2(aix, aiy); im[2 * k + 1] = mkv2(bix, biy);
  }
}

// Gate on a lane-bit qubit: transpose in, register gate, transpose out.
template <int W, int AS, int RS>
__device__ __forceinline__ void lanegate(v2 re[16], v2 im[16], const float2* g) {
  transpose_bit0<W, AS, RS>(re, im);
  const float2 u00 = g[0], u01 = g[1], u10 = g[2], u11 = g[3];
#pragma unroll
  for (int k = 0; k < 8; ++k)
    apply_pair(re[2 * k], im[2 * k], re[2 * k + 1], im[2 * k + 1], u00, u01, u10, u11);
  transpose_bit0<W, AS, RS>(re, im);
}

#define LOAD16(BASE, KARR)                                             \
  _Pragma("unroll")                                                    \
  for (int j = 0; j < 16; ++j) {                                       \
    const float4 v = *(const float4*)(st + ((BASE) ^ KTab.KARR[j]));   \
    re[j] = mkv2(v.x, v.y);                                            \
    im[j] = mkv2(v.z, v.w);                                            \
  }
#define STORE16(BASE, KARR)                                            \
  _Pragma("unroll")                                                    \
  for (int j = 0; j < 16; ++j)                                         \
    *(float4*)(st + ((BASE) ^ KTab.KARR[j])) =                         \
        make_float4(re[j].x, re[j].y, im[j].x, im[j].y);

// Full 4-layer circuit. P: qubits 3,2,1,0 (reg) + 5 (pl16@z6) + 4 (pl32@z7).
// Q: qubits 11,10,9,8 (reg) + 7 (pl16@z4) + 6 (pl32@z5).
template <int AS, int RS>
__device__ __forceinline__ void circuit(char* st, const float2* gmat,
                                        int basePb, int baseQb, int gbaseb) {
  v2 re[16], im[16];
  for (int L = 0; L < NLAYER; ++L) {
    const float2* GL = &gmat[L * NQ * 4];
    if (L == 0) {
      LOAD16(basePb, P)
    } else {
      LOAD16(gbaseb, G)   // fuses previous layer's CNOT permutation
    }
    gates4<3>(re, im, GL);
    lanegate<16, AS, RS>(re, im, &GL[5 * 4]);
    lanegate<32, AS, RS>(re, im, &GL[4 * 4]);
    if (L > 0) __syncthreads();  // all gathers consumed before in-place writes
    STORE16(basePb, P)
    __syncthreads();

    LOAD16(baseQb, Q)
    gates4<11>(re, im, GL);
    lanegate<16, AS, RS>(re, im, &GL[7 * 4]);
    lanegate<32, AS, RS>(re, im, &GL[6 * 4]);
    STORE16(baseQb, Q)
    __syncthreads();
  }
}

__global__ __launch_bounds__(NT, 2) void qsim_kernel(
    const float* __restrict__ x, const float* __restrict__ w,
    float* __restrict__ out) {
  extern __shared__ __align__(16) char smem[];
  char*   st   = smem;                           // 64 KB: unit=(re0,re1,im0,im1)
  float2* gmat = (float2*)(smem + DIM * 16);     // 1.5 KB
  v2*     red  = (v2*)(gmat + NLAYER * NQ * 4);  // 32 B

  const int t = threadIdx.x;
  const int lane = t & 63, w2 = t >> 6;
  const long r0 = 2L * blockIdx.x;

  // --- gate matrices (48 gates, one thread each) ---
  if (t < NLAYER * NQ) {
    const float* wp = w + t * 3;
    float phi = wp[0], th = wp[1], om = wp[2];
    float sn, cc, sa, ca, sb, cb;
    sincosf(0.5f * th, &sn, &cc);
    sincosf(0.5f * (phi + om), &sa, &ca);
    sincosf(0.5f * (phi - om), &sb, &cb);
    float2* g = &gmat[t * 4];
    g[0] = make_float2(ca * cc, -sa * cc);   // U00
    g[1] = make_float2(-cb * sn, -sb * sn);  // U01
    g[2] = make_float2(cb * sn, -sb * sn);   // U10
    g[3] = make_float2(ca * cc, sa * cc);    // U11
  }

  // --- load 16 consecutive x from each of 2 rows, norms ---
  const float4* xa = (const float4*)(x + r0 * DIM) + t * 4;
  const float4* xb = (const float4*)(x + (r0 + 1) * DIM) + t * 4;
  float va[16], vb[16];
#pragma unroll
  for (int k = 0; k < 4; ++k) {
    const float4 A = xa[k], Bv = xb[k];
    va[k * 4 + 0] = A.x;  va[k * 4 + 1] = A.y;
    va[k * 4 + 2] = A.z;  va[k * 4 + 3] = A.w;
    vb[k * 4 + 0] = Bv.x; vb[k * 4 + 1] = Bv.y;
    vb[k * 4 + 2] = Bv.z; vb[k * 4 + 3] = Bv.w;
  }
  v2 ss = sp(0.f);
#pragma unroll
  for (int e = 0; e < 16; ++e) { ss.x += va[e] * va[e]; ss.y += vb[e] * vb[e]; }
  const v2 nsq = block_reduce_sum2(ss, red);   // barriers also cover gmat init
  const float n0 = sqrtf(nsq.x), n1 = sqrtf(nsq.y);
  const bool ok0 = n0 > 1e-10f, ok1 = n1 > 1e-10f;
  const float i0f = ok0 ? 1.0f / n0 : 0.f, i1f = ok1 ? 1.0f / n1 : 0.f;

  // --- pattern bases (BYTE offsets; every access = base ^ compile-time K) ---
  // P: z = (lane&15) | w2<<4 | (lane>>4)<<6 | j<<8   (permlane bits z6,z7)
  // Q: z = j | (lane>>4)<<4 | (lane&15)<<6 | w2<<10  (permlane bits z4,z5)
  const int zP = (lane & 15) | (w2 << 4) | ((lane >> 4) << 6);
  const int basePb = swz_d(zP) << 4;
  const int baseQb = swz_d(((lane >> 4) << 4) | ((lane & 15) << 6) | (w2 << 10)) << 4;
  const int gbaseb = swz_d(sfun_d(zP)) << 4;
  const int baseEb = swz_d(t << 4) << 4;
  const int obaseb = swz_d(sfun_d(t)) << 4;

  // encode (pattern E = Q-offset table): logical z = t*16 + e
#pragma unroll
  for (int e = 0; e < 16; ++e)
    *(float4*)(st + (baseEb ^ KTab.Q[e])) =
        make_float4(ok0 ? va[e] * i0f : 0.015625f,
                    ok1 ? vb[e] * i1f : 0.015625f, 0.f, 0.f);
  __syncthreads();

  // --- probe permlane-swap convention (wave-uniform, one-time) ---
  // Lane payloads: a = 2*h (h = lane-bit4), b = 2*h + 1 (distinct regs).
  // At lane 16 (h=1) observe (r0, r1):
  //   canonical (AS0,RS0): r0 = a-result = 1  (old b of h=0), r1 = 2
  //   possibilities: (1,2)->AS0RS0 (2,1)->AS0RS1 (0,3)->AS1RS1 (3,0)->AS1RS0
  bool asw, rsw;
  {
    const float px = (lane & 16) ? 2.f : 0.f;
    const float py = px + 1.f;
    const u2 pr = __builtin_amdgcn_permlane16_swap(
        __builtin_bit_cast(unsigned, px), __builtin_bit_cast(unsigned, py),
        false, false);
    const float v0 = __shfl(__builtin_bit_cast(float, pr[0]), 16, 64);
    const float v1 = __shfl(__builtin_bit_cast(float, pr[1]), 16, 64);
    // AS1 cases have {v0,v1} = {0,3}; AS0 cases have {1,2}.
    asw = (v0 == 0.f || v0 == 3.f);
    // RS: canonical r0 should be the EVEN-coded (a-channel) result.
    // AS0: a-result=1, b-result=2 -> rsw = (v0==2). AS1: a-result(after arg
    // swap correction)=0? derive: AS1,RS0 gives (3,0) -> need swap -> rsw=(v0==3).
    rsw = asw ? (v0 == 3.f) : (v0 == 2.f);
  }
  if (asw) {
    if (rsw) circuit<1, 1>(st, gmat, basePb, baseQb, gbaseb);
    else     circuit<1, 0>(st, gmat, basePb, baseQb, gbaseb);
  } else {
    if (rsw) circuit<0, 1>(st, gmat, basePb, baseQb, gbaseb);
    else     circuit<0, 0>(st, gmat, basePb, baseQb, gbaseb);
  }

  // --- output: final perm fused into gather; probs + renormalize, 2 rows ---
  float q0[16], q1[16];
  v2 ps = sp(0.f);
#pragma unroll
  for (int k = 0; k < 16; ++k) {
    const float4 v = *(const float4*)(st + (obaseb ^ KTab.G[k]));
    q0[k] = v.x * v.x + v.z * v.z;
    q1[k] = v.y * v.y + v.w * v.w;
    ps.x += q0[k]; ps.y += q1[k];
  }
  const v2 tot = block_reduce_sum2(ps, red);
  const bool k0 = tot.x > 1e-10f, k1 = tot.y > 1e-10f;
  const float t0 = k0 ? 1.0f / tot.x : 0.f, t1 = k1 ? 1.0f / tot.y : 0.f;
  float* o0 = out + r0 * DIM;
  float* o1 = out + (r0 + 1) * DIM;
#pragma unroll
  for (int k = 0; k < 16; ++k) {
    o0[t + k * NT] = k0 ? q0[k] * t0 : (1.0f / DIM);
    o1[t + k * NT] = k1 ? q1[k] * t1 : (1.0f / DIM);
  }
}

extern "C" void kernel_launch(void* const* d_in, const int* in_sizes, int n_in,
                              void* d_out, int out_size, void* d_ws, size_t ws_size,
                              hipStream_t stream) {
  const float* x = (const float*)d_in[0];
  const float* w = (const float*)d_in[1];
  float* out = (float*)d_out;
  const int B = in_sizes[0] / DIM;
  const size_t smem = DIM * 16 + NLAYER * NQ * 4 * sizeof(float2)
                    + (NT / 64) * sizeof(v2);
  qsim_kernel<<<B / 2, NT, smem, stream>>>(x, w, out);
}